// Round 7
// baseline (211.234 us; speedup 1.0000x reference)
//
#include <hip/hip_runtime.h>

#define B 256
#define M 8
#define L 64
#define E 128
#define H 8
#define HD 16
#define NET 8
#define E3 384
#define NUM_NODES 200000
#define NT_FLOAT4 ((NUM_NODES * E) / 4)   // 6,400,000

// ---------------------------------------------------------------------------
// K0: streaming prefetch of node_table -> Infinity Cache (memory-side LLC).
// 2048 blocks x 256 thr, grid-stride float4, ~12 iters each, 102 MB total.
// Side job: transpose Wqkv/Wo into ws (first 65536 threads).
// ---------------------------------------------------------------------------
__global__ __launch_bounds__(256) void k_prefetch(
    const float4* __restrict__ nt4,
    const float* __restrict__ Wqkv, const float* __restrict__ Wo,
    float* __restrict__ WqkvT, float* __restrict__ WoT,
    float* __restrict__ sink) {
  int tid = blockIdx.x * 256 + threadIdx.x;    // 524288 threads

  if (tid < E * E3) {
    int e = tid / E3, o = tid - e * E3;
    WqkvT[tid] = Wqkv[o * E + e];
  } else if (tid < E * E3 + E * E) {
    int j = tid - E * E3;
    int e = j >> 7, o = j & 127;
    WoT[j] = Wo[o * E + e];
  }

  float s = 0.f;
  for (int i = tid; i < NT_FLOAT4; i += 2048 * 256) {
    float4 v = nt4[i];
    s += v.x + v.y + v.z + v.w;
  }
  if (s == 1234.5678f) sink[0] = s;   // keep loads alive; never taken in practice
}

// ---------------------------------------------------------------------------
// K1: gather + fuse + mean, one block per (b,m) pair (2048 blocks, 256 thr).
// 8 groups x 32 lanes; group owns 8 walk steps; 16-deep float4 load batch.
// After k_prefetch, the random row reads should hit the warm LLC.
// ---------------------------------------------------------------------------
__global__ __launch_bounds__(256, 4) void k_gather(
    const int* __restrict__ walks, const float* __restrict__ node_table,
    const float* __restrict__ fc1_b, const float* __restrict__ edge_table,
    float* __restrict__ agg0) {
  __shared__ int    s_idx[L][3];      // 768 B
  __shared__ float  s_et[NET * E];    // 4 KB
  __shared__ float4 s_red[8][32];     // 4 KB

  int r = blockIdx.x;                 // r = b*M + m
  int t = threadIdx.x;
  int g = t >> 5, lane = t & 31;

  if (t < L * 3) ((int*)s_idx)[t] = walks[r * (L * 3) + t];
  #pragma unroll
  for (int i = 0; i < 4; ++i) s_et[i * 256 + t] = edge_table[i * 256 + t];
  __syncthreads();

  const float4* nt4 = (const float4*)node_table;   // row stride 32 float4
  float4 fb = ((const float4*)fc1_b)[lane];
  float4 acc = make_float4(0.f, 0.f, 0.f, 0.f);
  {
    int l0 = g * 8;
    float4 a[8], c[8];
    #pragma unroll
    for (int i = 0; i < 8; ++i) {
      int n1 = s_idx[l0 + i][0];
      int n2 = s_idx[l0 + i][1];
      a[i] = nt4[n1 * 32 + lane];
      c[i] = nt4[n2 * 32 + lane];
    }
    #pragma unroll
    for (int i = 0; i < 8; ++i) {
      int et = s_idx[l0 + i][2];
      float4 ev = ((const float4*)(s_et + et * E))[lane];
      acc.x += (a[i].x + fb.x) * (c[i].x + fb.x) * ev.x;
      acc.y += (a[i].y + fb.y) * (c[i].y + fb.y) * ev.y;
      acc.z += (a[i].z + fb.z) * (c[i].z + fb.z) * ev.z;
      acc.w += (a[i].w + fb.w) * (c[i].w + fb.w) * ev.w;
    }
  }
  s_red[g][lane] = acc;
  __syncthreads();
  if (t < 32) {
    float4 s = s_red[0][t];
    #pragma unroll
    for (int gg = 1; gg < 8; ++gg) {
      float4 v = s_red[gg][t];
      s.x += v.x; s.y += v.y; s.z += v.z; s.w += v.w;
    }
    const float inv = 1.0f / (float)L;
    s.x *= inv; s.y *= inv; s.z *= inv; s.w *= inv;
    ((float4*)agg0)[r * 32 + t] = s;
  }
}

// ---------------------------------------------------------------------------
// K2: phases 2-5 (mp-linear, qkv, attention, out-proj), one block per b,
// 1024 threads.  Identical to the R4/R5-verified code.
// ---------------------------------------------------------------------------
__global__ __launch_bounds__(1024) void k_attn(
    const float* __restrict__ agg0, const int* __restrict__ mp_type_idx,
    const float* __restrict__ W_mp, const float* __restrict__ b_mp,
    const float* __restrict__ WqkvT, const float* __restrict__ bqkv,
    const float* __restrict__ WoT, const float* __restrict__ bo,
    float* __restrict__ out) {
  __shared__ float s_x[M][E];
  __shared__ float s_y[M][E];
  __shared__ float s_qkv[M][E3 + 1];
  __shared__ float s_sc[H][M][M];
  __shared__ float s_o[M][E];
  __shared__ int   s_mp[M];

  int b = blockIdx.x;
  int t = threadIdx.x;

  ((float*)s_x)[t] = agg0[b * (M * E) + t];    // M*E == 1024
  if (t < M) s_mp[t] = mp_type_idx[t];
  __syncthreads();

  // ---- phase 2: agg1 = agg0 @ W_mp[mp] + b_mp.  t = (m, o) scalar ----
  {
    int m = t >> 7, o = t & 127;
    int mp = s_mp[m];
    const float* W = W_mp + mp * E * E;
    float acc = 0.f;
    for (int e = 0; e < E; ++e)
      acc += s_x[m][e] * W[e * E + o];     // s_x broadcast; W coalesced
    s_y[m][o] = acc + b_mp[mp * E + o];
  }
  __syncthreads();

  // ---- phase 3: qkv = agg1 @ WqkvT + bqkv.  768 thr: (half, o), acc[4] ----
  if (t < 768) {
    int half = t / 384;          // wave-uniform (384 = 6 waves)
    int o = t - half * 384;
    float acc[4] = {0.f, 0.f, 0.f, 0.f};
    for (int e = 0; e < E; ++e) {
      float w = WqkvT[e * E3 + o];
      #pragma unroll
      for (int j = 0; j < 4; ++j) acc[j] += s_y[half * 4 + j][e] * w;
    }
    float bias = bqkv[o];
    #pragma unroll
    for (int j = 0; j < 4; ++j) s_qkv[half * 4 + j][o] = acc[j] + bias;
  }
  __syncthreads();

  // ---- phase 4a: scores[h][m][n] = q.k / sqrt(16) ----
  if (t < 512) {
    int h = t >> 6, mq = (t >> 3) & 7, n = t & 7;
    float s = 0.f;
    #pragma unroll
    for (int d = 0; d < HD; ++d)
      s += s_qkv[mq][h * HD + d] * s_qkv[n][E + h * HD + d];
    s_sc[h][mq][n] = s * 0.25f;
  }
  __syncthreads();

  // ---- phase 4b: softmax over n ----
  if (t < 64) {
    int h = t >> 3, mq = t & 7;
    float mx = -1e30f;
    #pragma unroll
    for (int n = 0; n < 8; ++n) mx = fmaxf(mx, s_sc[h][mq][n]);
    float ex[8];
    float sum = 0.f;
    #pragma unroll
    for (int n = 0; n < 8; ++n) { ex[n] = __expf(s_sc[h][mq][n] - mx); sum += ex[n]; }
    float inv = 1.0f / sum;
    #pragma unroll
    for (int n = 0; n < 8; ++n) s_sc[h][mq][n] = ex[n] * inv;
  }
  __syncthreads();

  // ---- phase 4c: o[m][col] = sum_n attn[h][m][n] * v[n][col] ----
  {
    int mq = t >> 7, col = t & 127, h = col >> 4;
    float s = 0.f;
    #pragma unroll
    for (int n = 0; n < 8; ++n)
      s += s_sc[h][mq][n] * s_qkv[n][2 * E + col];
    s_o[mq][col] = s;
  }
  __syncthreads();

  // ---- phase 5: out = o @ WoT + bo.  512 thr: (m-pair, o), acc[2] ----
  if (t < 512) {
    int pm = t >> 7, o = t & 127;
    float acc[2] = {0.f, 0.f};
    for (int e = 0; e < E; ++e) {
      float w = WoT[e * E + o];
      acc[0] += s_o[pm * 2][e] * w;
      acc[1] += s_o[pm * 2 + 1][e] * w;
    }
    float bias = bo[o];
    out[((pm * 2) * B + b) * E + o]     = acc[0] + bias;
    out[((pm * 2 + 1) * B + b) * E + o] = acc[1] + bias;
  }
}

// ---------------------------------------------------------------------------
extern "C" void kernel_launch(void* const* d_in, const int* in_sizes, int n_in,
                              void* d_out, int out_size, void* d_ws, size_t ws_size,
                              hipStream_t stream) {
  const int*   mp_type_idx = (const int*)d_in[1];
  const int*   walks       = (const int*)d_in[2];
  const float* node_table  = (const float*)d_in[3];
  const float* fc1_b       = (const float*)d_in[4];
  const float* edge_table  = (const float*)d_in[5];
  const float* W_mp        = (const float*)d_in[6];
  const float* b_mp        = (const float*)d_in[7];
  const float* Wqkv        = (const float*)d_in[8];
  const float* bqkv        = (const float*)d_in[9];
  const float* Wo          = (const float*)d_in[10];
  const float* bo          = (const float*)d_in[11];
  float* out = (float*)d_out;

  char* ws = (char*)d_ws;
  float* WqkvT = (float*)(ws);                    // 192 KB
  float* WoT   = (float*)(ws + (192 << 10));      // 64 KB
  float* agg0  = (float*)(ws + (256 << 10));      // 1 MB
  float* sink  = (float*)(ws + (2 << 20));

  k_prefetch<<<dim3(2048), dim3(256), 0, stream>>>(
      (const float4*)node_table, Wqkv, Wo, WqkvT, WoT, sink);
  k_gather<<<dim3(B * M), dim3(256), 0, stream>>>(
      walks, node_table, fc1_b, edge_table, agg0);
  k_attn<<<dim3(B), dim3(1024), 0, stream>>>(
      agg0, mp_type_idx, W_mp, b_mp, WqkvT, bqkv, WoT, bo, out);
}

// Round 8
// 189.581 us; speedup vs baseline: 1.1142x; 1.1142x over previous
//
#include <hip/hip_runtime.h>

#define B 256
#define M 8
#define L 64
#define E 128
#define H 8
#define HD 16
#define NET 8
#define E3 384

// ---------------------------------------------------------------------------
// K0: transpose Wqkv [384,128] -> WqkvT [128,384]; Wo [128,128] -> WoT [128,128]
// ---------------------------------------------------------------------------
__global__ __launch_bounds__(256) void k_transpose(
    const float* __restrict__ Wqkv, const float* __restrict__ Wo,
    float* __restrict__ WqkvT, float* __restrict__ WoT) {
  int idx = blockIdx.x * 256 + threadIdx.x;   // grid covers exactly 65536
  if (idx < E * E3) {
    int e = idx / E3;
    int o = idx - e * E3;
    WqkvT[idx] = Wqkv[o * E + e];
  } else {
    int j = idx - E * E3;                     // j < 16384
    int e = j >> 7, o = j & 127;
    WoT[j] = Wo[o * E + e];
  }
}

// ---------------------------------------------------------------------------
// K1 (fused, 1024 threads): one block per target node b; 16 waves/CU.
// Best-measured configuration (R4: 189.8 us total).
//   ph1: gather+fuse+mean   (32 groups = m x L-quarter)
//   ph2: mp-linear          (1024 thr = (m,o) scalar, coalesced W)
//   ph3: qkv proj           (768 thr = (m-half, o), acc[4] over m)
//   ph4: attention M=8,H=8  (LDS)
//   ph5: out proj           (512 thr = (m-pair, o), acc[2] over m)
// Gather phase sits at the probed random-512B-row ceiling (~1.5-1.7 TB/s,
// invariant to occupancy/depth/request-path/LLC-warmth — R4/R5/R6/R7).
// ---------------------------------------------------------------------------
__global__ __launch_bounds__(1024) void k_fused(
    const int* __restrict__ walks, const float* __restrict__ node_table,
    const float* __restrict__ fc1_b, const float* __restrict__ edge_table,
    const int* __restrict__ mp_type_idx,
    const float* __restrict__ W_mp, const float* __restrict__ b_mp,
    const float* __restrict__ WqkvT, const float* __restrict__ bqkv,
    const float* __restrict__ WoT, const float* __restrict__ bo,
    float* __restrict__ out) {
  __shared__ int    s_idx[M][L][3];      // 6 KB
  __shared__ float  s_et[NET * E];       // 4 KB
  __shared__ float4 s_red[32][32];       // 16 KB gather partials
  __shared__ float  s_x[M][E];           // agg0
  __shared__ float  s_y[M][E];           // agg1
  __shared__ float  s_qkv[M][E3 + 1];    // 12 KB
  __shared__ float  s_sc[H][M][M];
  __shared__ float  s_o[M][E];
  __shared__ int    s_mp[M];

  int b = blockIdx.x;
  int t = threadIdx.x;
  int g = t >> 5, lane = t & 31;

  // ---- stage walk indices / edge table / mp ids ----
  const int* wb = walks + b * (M * L * 3);
  for (int idx = t; idx < M * L * 3; idx += 1024) ((int*)s_idx)[idx] = wb[idx];
  s_et[t] = edge_table[t];               // NET*E == 1024
  if (t < M) s_mp[t] = mp_type_idx[t];
  __syncthreads();

  // ---- phase 1: gather + fuse + mean.  group g = (m, quarter q) ----
  {
    const float4* nt4 = (const float4*)node_table;   // row stride 32 float4
    float4 fb = ((const float4*)fc1_b)[lane];
    int m = g >> 2, q = g & 3;
    float4 acc = make_float4(0.f, 0.f, 0.f, 0.f);
    #pragma unroll
    for (int bi = 0; bi < 2; ++bi) {
      int l0 = q * 16 + bi * 8;
      float4 a[8], c[8];
      #pragma unroll
      for (int i = 0; i < 8; ++i) {
        int n1 = s_idx[m][l0 + i][0];
        int n2 = s_idx[m][l0 + i][1];
        a[i] = nt4[n1 * 32 + lane];
        c[i] = nt4[n2 * 32 + lane];
      }
      #pragma unroll
      for (int i = 0; i < 8; ++i) {
        int et = s_idx[m][l0 + i][2];
        float4 ev = ((const float4*)(s_et + et * E))[lane];
        acc.x += (a[i].x + fb.x) * (c[i].x + fb.x) * ev.x;
        acc.y += (a[i].y + fb.y) * (c[i].y + fb.y) * ev.y;
        acc.z += (a[i].z + fb.z) * (c[i].z + fb.z) * ev.z;
        acc.w += (a[i].w + fb.w) * (c[i].w + fb.w) * ev.w;
      }
    }
    s_red[g][lane] = acc;
  }
  __syncthreads();
  if (t < 256) {
    int m = t >> 5, ln = t & 31;
    float4 s = s_red[m * 4][ln];
    #pragma unroll
    for (int q = 1; q < 4; ++q) {
      float4 v = s_red[m * 4 + q][ln];
      s.x += v.x; s.y += v.y; s.z += v.z; s.w += v.w;
    }
    const float inv = 1.0f / (float)L;
    s.x *= inv; s.y *= inv; s.z *= inv; s.w *= inv;
    ((float4*)s_x[m])[ln] = s;
  }
  __syncthreads();

  // ---- phase 2: agg1 = agg0 @ W_mp[mp] + b_mp.  t = (m, o) scalar ----
  {
    int m = t >> 7, o = t & 127;
    int mp = s_mp[m];
    const float* W = W_mp + mp * E * E;
    float acc = 0.f;
    for (int e = 0; e < E; ++e)
      acc += s_x[m][e] * W[e * E + o];     // s_x broadcast; W coalesced
    s_y[m][o] = acc + b_mp[mp * E + o];
  }
  __syncthreads();

  // ---- phase 3: qkv = agg1 @ WqkvT + bqkv.  768 thr: (half, o), acc[4] ----
  if (t < 768) {
    int half = t / 384;          // wave-uniform (384 = 6 waves)
    int o = t - half * 384;
    float acc[4] = {0.f, 0.f, 0.f, 0.f};
    for (int e = 0; e < E; ++e) {
      float w = WqkvT[e * E3 + o];
      #pragma unroll
      for (int j = 0; j < 4; ++j) acc[j] += s_y[half * 4 + j][e] * w;
    }
    float bias = bqkv[o];
    #pragma unroll
    for (int j = 0; j < 4; ++j) s_qkv[half * 4 + j][o] = acc[j] + bias;
  }
  __syncthreads();

  // ---- phase 4a: scores[h][m][n] = q.k / sqrt(16) ----
  if (t < 512) {
    int h = t >> 6, mq = (t >> 3) & 7, n = t & 7;
    float s = 0.f;
    #pragma unroll
    for (int d = 0; d < HD; ++d)
      s += s_qkv[mq][h * HD + d] * s_qkv[n][E + h * HD + d];
    s_sc[h][mq][n] = s * 0.25f;
  }
  __syncthreads();

  // ---- phase 4b: softmax over n ----
  if (t < 64) {
    int h = t >> 3, mq = t & 7;
    float mx = -1e30f;
    #pragma unroll
    for (int n = 0; n < 8; ++n) mx = fmaxf(mx, s_sc[h][mq][n]);
    float ex[8];
    float sum = 0.f;
    #pragma unroll
    for (int n = 0; n < 8; ++n) { ex[n] = __expf(s_sc[h][mq][n] - mx); sum += ex[n]; }
    float inv = 1.0f / sum;
    #pragma unroll
    for (int n = 0; n < 8; ++n) s_sc[h][mq][n] = ex[n] * inv;
  }
  __syncthreads();

  // ---- phase 4c: o[m][col] = sum_n attn[h][m][n] * v[n][col] ----
  {
    int mq = t >> 7, col = t & 127, h = col >> 4;
    float s = 0.f;
    #pragma unroll
    for (int n = 0; n < 8; ++n)
      s += s_sc[h][mq][n] * s_qkv[n][2 * E + col];
    s_o[mq][col] = s;
  }
  __syncthreads();

  // ---- phase 5: out = o @ WoT + bo.  512 thr: (m-pair, o), acc[2] ----
  if (t < 512) {
    int pm = t >> 7, o = t & 127;
    float acc[2] = {0.f, 0.f};
    for (int e = 0; e < E; ++e) {
      float w = WoT[e * E + o];
      acc[0] += s_o[pm * 2][e] * w;
      acc[1] += s_o[pm * 2 + 1][e] * w;
    }
    float bias = bo[o];
    out[((pm * 2) * B + b) * E + o]     = acc[0] + bias;
    out[((pm * 2 + 1) * B + b) * E + o] = acc[1] + bias;
  }
}

// ---------------------------------------------------------------------------
extern "C" void kernel_launch(void* const* d_in, const int* in_sizes, int n_in,
                              void* d_out, int out_size, void* d_ws, size_t ws_size,
                              hipStream_t stream) {
  const int*   mp_type_idx = (const int*)d_in[1];
  const int*   walks       = (const int*)d_in[2];
  const float* node_table  = (const float*)d_in[3];
  const float* fc1_b       = (const float*)d_in[4];
  const float* edge_table  = (const float*)d_in[5];
  const float* W_mp        = (const float*)d_in[6];
  const float* b_mp        = (const float*)d_in[7];
  const float* Wqkv        = (const float*)d_in[8];
  const float* bqkv        = (const float*)d_in[9];
  const float* Wo          = (const float*)d_in[10];
  const float* bo          = (const float*)d_in[11];
  float* out = (float*)d_out;

  char* ws = (char*)d_ws;
  float* WqkvT = (float*)(ws);                    // 192 KB
  float* WoT   = (float*)(ws + (256 << 10));      // 64 KB

  k_transpose<<<dim3(256), dim3(256), 0, stream>>>(Wqkv, Wo, WqkvT, WoT);
  k_fused<<<dim3(B), dim3(1024), 0, stream>>>(
      walks, node_table, fc1_b, edge_table, mp_type_idx,
      W_mp, b_mp, WqkvT, bqkv, WoT, bo, out);
}